// Round 20
// baseline (32.245 us; speedup 1.0000x reference)
//
#include <hip/hip_runtime.h>
#include <stdint.h>

// AeTransformer_44839458570443: 3-NN inverse-distance interpolation + (tanh+1)/2.
// xyz1: [B,3,N] fp32, xyz2: [B,3,S] fp32, points2: [B,1,S] fp32 -> out [B,N] fp32.
//
// Selection bit-matches the reference fp32 expanded distance
//   d = (-2*((x*x'+y*y')+z*z') + ||q||^2) + ||p||^2   (fp32, no FMA)
// ordered by (d, index).
//
// Round 20 = Round 19 + VGPR diet. R19 was occupancy-capped by VGPR (~190 ->
// 2 waves/SIMD; LDS 48KB would allow 3 blocks/CU). Phase A only needs
// {nxp,nyp,nzp,c,keys} per slot; the {x,y,z,ss,nx,ny,nz} consumed in phase C
// (7 regs x 8 slots = 56 VGPRs) are dropped and RELOADED from global (L1-hot,
// 6 coalesced dwords for the wave's 2 owned slots) after the final barrier,
// recomputed with the identical IEEE chain (bit-identical). ~150 VGPR ->
// __launch_bounds__(256,3) -> 3 waves/SIMD (+50% latency hiding).
// PHASE A (proxy, pk-fma): Q=8 x split-4; per group of 8, packed distances +
//   min tree -> group min; 5 best (group-min | gid) keys per slot. Lemma: at
//   most 3 groups can have min <= d3; 5 kept for margin.
// MERGE: wave w owns slots 2w,2w+1; INS5-merges 3 partners' lists via LDS.
// PHASE C (LDS AoS gathers): proxy rescan of 40 survivors, 9-bit 6-slot
//   screen, exact replicated ref_d on 6, (d,idx) sort, replicated fp32
//   weight chain (proven R2-R19).
static constexpr int B = 4;
static constexpr int N = 65536;
static constexpr int S = 512;

typedef float float2v __attribute__((ext_vector_type(2)));

// Reference-replicated fp32 distance (numpy order, no contraction)
__device__ __forceinline__ float ref_d(float x1, float y1, float z1, float ssrc, float4 p) {
    float dot = __fadd_rn(__fadd_rn(__fmul_rn(x1, p.x), __fmul_rn(y1, p.y)),
                          __fmul_rn(z1, p.z));
    float t = __fmul_rn(dot, -2.0f);
    return __fadd_rn(__fadd_rn(t, ssrc), p.w);
}

#define CAS(da_, ia_, db_, ib_)                                     \
    {                                                               \
        bool sw_ = (db_ < da_) || ((db_ == da_) && (ib_ < ia_));    \
        float tda_ = sw_ ? db_ : da_;                               \
        int tia_ = sw_ ? ib_ : ia_;                                 \
        db_ = sw_ ? da_ : db_;                                      \
        ib_ = sw_ ? ib_ : ib_;                                      \
        db_ = sw_ ? da_ : db_;                                      \
        ib_ = sw_ ? ia_ : ib_;                                      \
        da_ = tda_;                                                 \
        ia_ = tia_;                                                 \
    }
#undef CAS
#define CAS(da_, ia_, db_, ib_)                                     \
    {                                                               \
        bool sw_ = (db_ < da_) || ((db_ == da_) && (ib_ < ia_));    \
        float tda_ = sw_ ? db_ : da_;                               \
        int tia_ = sw_ ? ib_ : ia_;                                 \
        db_ = sw_ ? da_ : db_;                                      \
        ib_ = sw_ ? ia_ : ib_;                                      \
        da_ = tda_;                                                 \
        ia_ = tia_;                                                 \
    }

// sorted insert into ascending 5-list (named slots)
#define INS5L(A0, A1, A2, A3, A4, k)                                \
    {                                                               \
        float t4 = __builtin_amdgcn_fmed3f(A3, (k), A4);            \
        float t3 = __builtin_amdgcn_fmed3f(A2, (k), A3);            \
        float t2 = __builtin_amdgcn_fmed3f(A1, (k), A2);            \
        float t1 = __builtin_amdgcn_fmed3f(A0, (k), A1);            \
        A0 = fminf(A0, (k));                                        \
        A1 = t1; A2 = t2; A3 = t3; A4 = t4;                         \
    }

#define INS6(k)                                                     \
    {                                                               \
        float t5 = __builtin_amdgcn_fmed3f(m4, (k), m5);            \
        float t4 = __builtin_amdgcn_fmed3f(m3, (k), m4);            \
        float t3 = __builtin_amdgcn_fmed3f(m2, (k), m3);            \
        float t2 = __builtin_amdgcn_fmed3f(m1, (k), m2);            \
        float t1 = __builtin_amdgcn_fmed3f(m0, (k), m1);            \
        m0 = fminf(m0, (k));                                        \
        m1 = t1; m2 = t2; m3 = t3; m4 = t4; m5 = t5;                \
    }

// Packed phase-A body for slot s; xs/ys/zs/ww are float2v[4] pairs
#define PK_PROC(s, gid)                                                       \
    {                                                                         \
        float2v e0 = __builtin_elementwise_fma(                               \
            nxp_##s, xs[0], __builtin_elementwise_fma(                        \
                                nyp_##s, ys[0],                               \
                                __builtin_elementwise_fma(nzp_##s, zs[0],     \
                                                          ww[0])));           \
        float2v e1 = __builtin_elementwise_fma(                               \
            nxp_##s, xs[1], __builtin_elementwise_fma(                        \
                                nyp_##s, ys[1],                               \
                                __builtin_elementwise_fma(nzp_##s, zs[1],     \
                                                          ww[1])));           \
        float2v e2 = __builtin_elementwise_fma(                               \
            nxp_##s, xs[2], __builtin_elementwise_fma(                        \
                                nyp_##s, ys[2],                               \
                                __builtin_elementwise_fma(nzp_##s, zs[2],     \
                                                          ww[2])));           \
        float2v e3 = __builtin_elementwise_fma(                               \
            nxp_##s, xs[3], __builtin_elementwise_fma(                        \
                                nyp_##s, ys[3],                               \
                                __builtin_elementwise_fma(nzp_##s, zs[3],     \
                                                          ww[3])));           \
        float2v mA = __builtin_elementwise_min(e0, e1);                       \
        float2v mB = __builtin_elementwise_min(e2, e3);                       \
        float2v mC = __builtin_elementwise_min(mA, mB);                       \
        float gm = fminf(mC.x, mC.y);                                         \
        uint32_t kb = (__float_as_uint(gm + c_##s) & maskA) | (uint32_t)(gid);\
        float gkey = __uint_as_float(kb);                                     \
        INS5L(k##s##0, k##s##1, k##s##2, k##s##3, k##s##4, gkey);             \
    }

// Phase C + refine + epilogue for slot s. Query coords reloaded from global
// (L1-hot; identical values) and constants recomputed with the identical
// IEEE chain -> selection and output bit-identical to R19.
#define PHASE_C(s)                                                            \
    {                                                                         \
        float X1 = q[n_0 + 64 * (s)];                                         \
        float Y1 = q[n_0 + 64 * (s) + N];                                     \
        float Z1 = q[n_0 + 64 * (s) + 2 * N];                                 \
        float SS = __fadd_rn(__fadd_rn(__fmul_rn(X1, X1), __fmul_rn(Y1, Y1)), \
                             __fmul_rn(Z1, Z1));                              \
        float CC = c_##s;                                                     \
        float NX = -2.0f * X1, NY = -2.0f * Y1, NZ = -2.0f * Z1;              \
        float m0 = 3.0e38f, m1 = 3.0e38f, m2 = 3.0e38f,                       \
              m3 = 3.0e38f, m4 = 3.0e38f, m5 = 3.0e38f;                       \
        float gkeys[5] = {k##s##0, k##s##1, k##s##2, k##s##3, k##s##4};       \
        _Pragma("unroll") for (int t = 0; t < 5; ++t) {                       \
            int gbase = (int)(__float_as_uint(gkeys[t]) & 63u) << 3;          \
            _Pragma("unroll") for (int j = 0; j < 8; ++j) {                   \
                float4 p = tileA[gbase + j]; /* divergent LDS gather */       \
                float e2 = fmaf(NX, p.x,                                      \
                                fmaf(NY, p.y, fmaf(NZ, p.z, p.w + CC)));      \
                float k = __uint_as_float((__float_as_uint(e2) & 0xFFFFFE00u) \
                                          | (uint32_t)(gbase + j));           \
                INS6(k);                                                      \
            }                                                                 \
        }                                                                     \
        int gi[6];                                                            \
        float dd[6];                                                          \
        gi[0] = (int)(__float_as_uint(m0) & 511u);                            \
        gi[1] = (int)(__float_as_uint(m1) & 511u);                            \
        gi[2] = (int)(__float_as_uint(m2) & 511u);                            \
        gi[3] = (int)(__float_as_uint(m3) & 511u);                            \
        gi[4] = (int)(__float_as_uint(m4) & 511u);                            \
        gi[5] = (int)(__float_as_uint(m5) & 511u);                            \
        _Pragma("unroll") for (int j = 0; j < 6; ++j)                         \
            dd[j] = ref_d(X1, Y1, Z1, SS, tileA[gi[j]]);                      \
        _Pragma("unroll") for (int pp = 0; pp < 3; ++pp)                      \
            _Pragma("unroll") for (int i = 4; i >= pp; --i)                   \
                CAS(dd[i], gi[i], dd[i + 1], gi[i + 1]);                      \
        const float EPS32 = 1e-8f;                                            \
        float r0 = __fdiv_rn(1.0f, __fadd_rn(dd[0], EPS32));                  \
        float r1 = __fdiv_rn(1.0f, __fadd_rn(dd[1], EPS32));                  \
        float r2 = __fdiv_rn(1.0f, __fadd_rn(dd[2], EPS32));                  \
        float rs = __fadd_rn(__fadd_rn(r0, r1), r2);                          \
        float w0 = __fdiv_rn(r0, rs);                                         \
        float w1 = __fdiv_rn(r1, rs);                                         \
        float w2 = __fdiv_rn(r2, rs);                                         \
        float interp = __fadd_rn(__fadd_rn(__fmul_rn(f[gi[0]], w0),           \
                                           __fmul_rn(f[gi[1]], w1)),          \
                                 __fmul_rn(f[gi[2]], w2));                    \
        float th = tanhf(interp);                                             \
        out[((size_t)b << 16) | (uint32_t)(n_0 + 64 * (s))] =                 \
            __fmul_rn(__fadd_rn(th, 1.0f), 0.5f);                             \
    }

// Merge 3 partner lists for slot s (partner wave bases P0,P1,P2) + phase C
#define FIN(s, P0, P1, P2)                                                    \
    {                                                                         \
        _Pragma("unroll") for (int j = 0; j < 5; ++j) {                       \
            float q0 = keys[(s) * 5 + j][lane + (P0)];                        \
            float q1 = keys[(s) * 5 + j][lane + (P1)];                        \
            float q2 = keys[(s) * 5 + j][lane + (P2)];                        \
            INS5L(k##s##0, k##s##1, k##s##2, k##s##3, k##s##4, q0);           \
            INS5L(k##s##0, k##s##1, k##s##2, k##s##3, k##s##4, q1);           \
            INS5L(k##s##0, k##s##1, k##s##2, k##s##3, k##s##4, q2);           \
        }                                                                     \
        PHASE_C(s);                                                           \
    }

__global__ __launch_bounds__(256, 3) void knn3_kernel(const float* __restrict__ xyz1,
                                                      const float* __restrict__ xyz2,
                                                      const float* __restrict__ points2,
                                                      float* __restrict__ out) {
    // 48 KB pool: tileA [0,8K) whole kernel; tile2 [8K,16K) dead after phase
    // A; keys rows (40 x 256 floats = 40K) overlay [8K,48K), barrier-guarded.
    __shared__ __align__(16) char smem[49152];
    float4* tileA = (float4*)smem;                       // AoS, phase C/refine
    float4* tile2 = (float4*)(smem + 8192);              // pair-SoA, phase A
    float (*keys)[256] = (float(*)[256])(smem + 8192);   // 40 rows x 256

    const int tid = threadIdx.x;
    const int lane = tid & 63;
    const int wid_u = __builtin_amdgcn_readfirstlane(tid >> 6);  // wave 0-3
    const int b = blockIdx.x >> 7;             // 128 blocks per batch
    const int base = (blockIdx.x & 127) << 9;  // block covers 512 queries

    // ---- fused prep: build both table layouts from xyz2 (bit-identical) ----
    {
        const float* p = xyz2 + (size_t)b * 3 * S;
        float* t2f = (float*)tile2;
#pragma unroll
        for (int r = 0; r < 2; ++r) {
            int s = tid + r * 256;
            float x = p[s], y = p[s + S], z = p[s + 2 * S];
            float c = __fadd_rn(__fadd_rn(__fmul_rn(x, x), __fmul_rn(y, y)),
                                __fmul_rn(z, z));
            tileA[s] = make_float4(x, y, z, c);
            int pp = s >> 1, h = s & 1;
            t2f[pp * 8 + 0 + h] = x;
            t2f[pp * 8 + 2 + h] = y;
            t2f[pp * 8 + 4 + h] = z;
            t2f[pp * 8 + 6 + h] = c;
        }
    }
    __syncthreads();

    // 8 query slots per lane; phase A keeps ONLY {nxp,nyp,nzp,c,keys}/slot
    const int n_0 = base + lane;
    const float* q = xyz1 + (size_t)b * 3 * N;
#define MKC(s)                                                                     \
    float c_##s;                                                                   \
    float2v nxp_##s, nyp_##s, nzp_##s;                                             \
    {                                                                              \
        float x = q[n_0 + 64 * s], y = q[n_0 + 64 * s + N],                        \
              z = q[n_0 + 64 * s + 2 * N];                                         \
        float ss = __fadd_rn(__fadd_rn(__fmul_rn(x, x), __fmul_rn(y, y)),          \
                             __fmul_rn(z, z));                                     \
        c_##s = ss + 0.25f;                                                        \
        float nx = -2.0f * x, ny = -2.0f * y, nz = -2.0f * z;                      \
        nxp_##s = (float2v){nx, nx};                                               \
        nyp_##s = (float2v){ny, ny};                                               \
        nzp_##s = (float2v){nz, nz};                                               \
    }                                                                              \
    float k##s##0 = 3.0e38f, k##s##1 = 3.0e38f, k##s##2 = 3.0e38f,                 \
          k##s##3 = 3.0e38f, k##s##4 = 3.0e38f;
    MKC(0) MKC(1) MKC(2) MKC(3) MKC(4) MKC(5) MKC(6) MKC(7)
#undef MKC

    uint32_t maskA = 0xFFFFFFC0u;     // VGPR mask -> single v_and_or_b32
    asm volatile("" : "+v"(maskA));

    // ---- Phase A: scan own 16 groups (pk distances); 5 best per slot ----
    const int gid0 = wid_u << 4;
#pragma unroll 2
    for (int g = 0; g < 16; ++g) {
        const int gid = gid0 + g;
        // group = 4 candidate pairs = 8 float4 (pair-SoA), broadcast b128
        float2v xs[4], ys[4], zs[4], ww[4];
#pragma unroll
        for (int k = 0; k < 4; ++k) {
            float4 pa = tile2[gid * 8 + 2 * k];      // {x_e,x_o,y_e,y_o}
            float4 pb = tile2[gid * 8 + 2 * k + 1];  // {z_e,z_o,w_e,w_o}
            xs[k] = (float2v){pa.x, pa.y};
            ys[k] = (float2v){pa.z, pa.w};
            zs[k] = (float2v){pb.x, pb.y};
            ww[k] = (float2v){pb.z, pb.w};
        }
        PK_PROC(0, gid) PK_PROC(1, gid) PK_PROC(2, gid) PK_PROC(3, gid)
        PK_PROC(4, gid) PK_PROC(5, gid) PK_PROC(6, gid) PK_PROC(7, gid)
    }

    // tile2 dead; keys overlay its space. Barrier so no wave still reads it.
    __syncthreads();

    // ---- publish all 40 keys ----
#define PUB(s)                                                       \
    keys[s * 5 + 0][tid] = k##s##0; keys[s * 5 + 1][tid] = k##s##1;  \
    keys[s * 5 + 2][tid] = k##s##2; keys[s * 5 + 3][tid] = k##s##3;  \
    keys[s * 5 + 4][tid] = k##s##4;
    PUB(0) PUB(1) PUB(2) PUB(3) PUB(4) PUB(5) PUB(6) PUB(7)
#undef PUB
    __syncthreads();

    // ---- merge + phase C: wave w owns slots 2w, 2w+1 ----
    const float* f = points2 + (size_t)b * S;  // D = 1
    if (wid_u == 0) {
        FIN(0, 64, 128, 192)
        FIN(1, 64, 128, 192)
    } else if (wid_u == 1) {
        FIN(2, 0, 128, 192)
        FIN(3, 0, 128, 192)
    } else if (wid_u == 2) {
        FIN(4, 0, 64, 192)
        FIN(5, 0, 64, 192)
    } else {
        FIN(6, 0, 64, 128)
        FIN(7, 0, 64, 128)
    }
}

extern "C" void kernel_launch(void* const* d_in, const int* in_sizes, int n_in,
                              void* d_out, int out_size, void* d_ws, size_t ws_size,
                              hipStream_t stream) {
    const float* xyz1 = (const float*)d_in[0];
    const float* xyz2 = (const float*)d_in[1];
    const float* points2 = (const float*)d_in[2];
    float* out = (float*)d_out;
    (void)d_ws; (void)ws_size;

    // 512 blocks x 256 threads: block covers 512 queries (Q=8 per lane),
    // candidates split 4 ways across the block's waves
    knn3_kernel<<<(B * N) / 512, 256, 0, stream>>>(xyz1, xyz2, points2, out);
}

// Round 21
// 29.481 us; speedup vs baseline: 1.0938x; 1.0938x over previous
//
#include <hip/hip_runtime.h>
#include <stdint.h>

// AeTransformer_44839458570443: 3-NN inverse-distance interpolation + (tanh+1)/2.
// xyz1: [B,3,N] fp32, xyz2: [B,3,S] fp32, points2: [B,1,S] fp32 -> out [B,N] fp32.
//
// Selection bit-matches the reference fp32 expanded distance
//   d = (-2*((x*x'+y*y')+z*z') + ||q||^2) + ||p||^2   (fp32, no FMA)
// ordered by (d, index).
//
// Round 21 = Round 19 (best, 31.8us) + ONE change: lane-rotated phase-C
// gather order. gbase is a multiple of 8, so tileA[gbase+j] puts ALL 64
// lanes on the same 4-bank quad for fixed j (dword off mod 32 = j*4+0..3)
// -> ~16+-round serialization x 40 instrs (R7's 5.07M-conflict signature).
// Lane i now reads j' = (j+lane)&7: quad = ((j+lane) mod 8)*4 spreads the
// wave over all 32 banks (~8-way, ~2.9x base per m136). Legal because the
// 6-slot screen inserts a SET of unique keys (order-independent min-6) and
// the refine re-sorts by (d,idx) -> output bit-identical.
// PHASE A (proxy, pk-fma): Q=8 x split-4; per group of 8, packed distances +
//   min tree -> group min; 5 best (group-min | gid) keys per slot. Lemma: at
//   most 3 groups can have min <= d3; 5 kept for margin.
// MERGE: wave w owns slots 2w,2w+1; INS5-merges 3 partners' lists via LDS.
// PHASE C (LDS AoS gathers, lane-rotated): proxy rescan of 40 survivors,
//   9-bit 6-slot screen, exact replicated ref_d on 6, (d,idx) sort,
//   replicated fp32 weight chain (proven R2-R20).
static constexpr int B = 4;
static constexpr int N = 65536;
static constexpr int S = 512;

typedef float float2v __attribute__((ext_vector_type(2)));

// Reference-replicated fp32 distance (numpy order, no contraction)
__device__ __forceinline__ float ref_d(float x1, float y1, float z1, float ssrc, float4 p) {
    float dot = __fadd_rn(__fadd_rn(__fmul_rn(x1, p.x), __fmul_rn(y1, p.y)),
                          __fmul_rn(z1, p.z));
    float t = __fmul_rn(dot, -2.0f);
    return __fadd_rn(__fadd_rn(t, ssrc), p.w);
}

#define CAS(da_, ia_, db_, ib_)                                     \
    {                                                               \
        bool sw_ = (db_ < da_) || ((db_ == da_) && (ib_ < ia_));    \
        float tda_ = sw_ ? db_ : da_;                               \
        int tia_ = sw_ ? ib_ : ia_;                                 \
        db_ = sw_ ? da_ : db_;                                      \
        ib_ = sw_ ? ia_ : ib_;                                      \
        da_ = tda_;                                                 \
        ia_ = tia_;                                                 \
    }

// sorted insert into ascending 5-list (named slots)
#define INS5L(A0, A1, A2, A3, A4, k)                                \
    {                                                               \
        float t4 = __builtin_amdgcn_fmed3f(A3, (k), A4);            \
        float t3 = __builtin_amdgcn_fmed3f(A2, (k), A3);            \
        float t2 = __builtin_amdgcn_fmed3f(A1, (k), A2);            \
        float t1 = __builtin_amdgcn_fmed3f(A0, (k), A1);            \
        A0 = fminf(A0, (k));                                        \
        A1 = t1; A2 = t2; A3 = t3; A4 = t4;                         \
    }

#define INS6(k)                                                     \
    {                                                               \
        float t5 = __builtin_amdgcn_fmed3f(m4, (k), m5);            \
        float t4 = __builtin_amdgcn_fmed3f(m3, (k), m4);            \
        float t3 = __builtin_amdgcn_fmed3f(m2, (k), m3);            \
        float t2 = __builtin_amdgcn_fmed3f(m1, (k), m2);            \
        float t1 = __builtin_amdgcn_fmed3f(m0, (k), m1);            \
        m0 = fminf(m0, (k));                                        \
        m1 = t1; m2 = t2; m3 = t3; m4 = t4; m5 = t5;                \
    }

// Packed phase-A body for slot s; xs/ys/zs/ww are float2v[4] pairs
#define PK_PROC(s, gid)                                                       \
    {                                                                         \
        float2v e0 = __builtin_elementwise_fma(                               \
            nxp_##s, xs[0], __builtin_elementwise_fma(                        \
                                nyp_##s, ys[0],                               \
                                __builtin_elementwise_fma(nzp_##s, zs[0],     \
                                                          ww[0])));           \
        float2v e1 = __builtin_elementwise_fma(                               \
            nxp_##s, xs[1], __builtin_elementwise_fma(                        \
                                nyp_##s, ys[1],                               \
                                __builtin_elementwise_fma(nzp_##s, zs[1],     \
                                                          ww[1])));           \
        float2v e2 = __builtin_elementwise_fma(                               \
            nxp_##s, xs[2], __builtin_elementwise_fma(                        \
                                nyp_##s, ys[2],                               \
                                __builtin_elementwise_fma(nzp_##s, zs[2],     \
                                                          ww[2])));           \
        float2v e3 = __builtin_elementwise_fma(                               \
            nxp_##s, xs[3], __builtin_elementwise_fma(                        \
                                nyp_##s, ys[3],                               \
                                __builtin_elementwise_fma(nzp_##s, zs[3],     \
                                                          ww[3])));           \
        float2v mA = __builtin_elementwise_min(e0, e1);                       \
        float2v mB = __builtin_elementwise_min(e2, e3);                       \
        float2v mC = __builtin_elementwise_min(mA, mB);                       \
        float gm = fminf(mC.x, mC.y);                                         \
        uint32_t kb = (__float_as_uint(gm + c_##s) & maskA) | (uint32_t)(gid);\
        float gkey = __uint_as_float(kb);                                     \
        INS5L(k##s##0, k##s##1, k##s##2, k##s##3, k##s##4, gkey);             \
    }

// Phase C + refine + epilogue for slot s (lane-rotated gather order)
#define PHASE_C(s)                                                            \
    {                                                                         \
        float m0 = 3.0e38f, m1 = 3.0e38f, m2 = 3.0e38f,                       \
              m3 = 3.0e38f, m4 = 3.0e38f, m5 = 3.0e38f;                       \
        float gkeys[5] = {k##s##0, k##s##1, k##s##2, k##s##3, k##s##4};       \
        _Pragma("unroll") for (int t = 0; t < 5; ++t) {                       \
            int gbase = (int)(__float_as_uint(gkeys[t]) & 63u) << 3;          \
            _Pragma("unroll") for (int jj = 0; jj < 8; ++jj) {                \
                int j = (jj + lane) & 7;     /* bank-spread rotation */       \
                float4 p = tileA[gbase + j]; /* divergent LDS gather */       \
                float e2 = fmaf(nx_##s, p.x,                                  \
                                fmaf(ny_##s, p.y,                             \
                                     fmaf(nz_##s, p.z, p.w + c_##s)));        \
                float k = __uint_as_float((__float_as_uint(e2) & 0xFFFFFE00u) \
                                          | (uint32_t)(gbase + j));           \
                INS6(k);                                                      \
            }                                                                 \
        }                                                                     \
        int gi[6];                                                            \
        float dd[6];                                                          \
        gi[0] = (int)(__float_as_uint(m0) & 511u);                            \
        gi[1] = (int)(__float_as_uint(m1) & 511u);                            \
        gi[2] = (int)(__float_as_uint(m2) & 511u);                            \
        gi[3] = (int)(__float_as_uint(m3) & 511u);                            \
        gi[4] = (int)(__float_as_uint(m4) & 511u);                            \
        gi[5] = (int)(__float_as_uint(m5) & 511u);                            \
        _Pragma("unroll") for (int j = 0; j < 6; ++j)                         \
            dd[j] = ref_d(x_##s, y_##s, z_##s, ss_##s, tileA[gi[j]]);         \
        _Pragma("unroll") for (int pp = 0; pp < 3; ++pp)                      \
            _Pragma("unroll") for (int i = 4; i >= pp; --i)                   \
                CAS(dd[i], gi[i], dd[i + 1], gi[i + 1]);                      \
        const float EPS32 = 1e-8f;                                            \
        float r0 = __fdiv_rn(1.0f, __fadd_rn(dd[0], EPS32));                  \
        float r1 = __fdiv_rn(1.0f, __fadd_rn(dd[1], EPS32));                  \
        float r2 = __fdiv_rn(1.0f, __fadd_rn(dd[2], EPS32));                  \
        float rs = __fadd_rn(__fadd_rn(r0, r1), r2);                          \
        float w0 = __fdiv_rn(r0, rs);                                         \
        float w1 = __fdiv_rn(r1, rs);                                         \
        float w2 = __fdiv_rn(r2, rs);                                         \
        float interp = __fadd_rn(__fadd_rn(__fmul_rn(f[gi[0]], w0),           \
                                           __fmul_rn(f[gi[1]], w1)),          \
                                 __fmul_rn(f[gi[2]], w2));                    \
        float th = tanhf(interp);                                             \
        out[((size_t)b << 16) | (uint32_t)(n_0 + 64 * (s))] =                 \
            __fmul_rn(__fadd_rn(th, 1.0f), 0.5f);                             \
    }

// Merge 3 partner lists for slot s (partner wave bases P0,P1,P2) + phase C
#define FIN(s, P0, P1, P2)                                                    \
    {                                                                         \
        _Pragma("unroll") for (int j = 0; j < 5; ++j) {                       \
            float q0 = keys[(s) * 5 + j][lane + (P0)];                        \
            float q1 = keys[(s) * 5 + j][lane + (P1)];                        \
            float q2 = keys[(s) * 5 + j][lane + (P2)];                        \
            INS5L(k##s##0, k##s##1, k##s##2, k##s##3, k##s##4, q0);           \
            INS5L(k##s##0, k##s##1, k##s##2, k##s##3, k##s##4, q1);           \
            INS5L(k##s##0, k##s##1, k##s##2, k##s##3, k##s##4, q2);           \
        }                                                                     \
        PHASE_C(s);                                                           \
    }

__global__ __launch_bounds__(256, 2) void knn3_kernel(const float* __restrict__ xyz1,
                                                      const float* __restrict__ xyz2,
                                                      const float* __restrict__ points2,
                                                      float* __restrict__ out) {
    // 48 KB pool: tileA [0,8K) whole kernel; tile2 [8K,16K) dead after phase
    // A; keys rows (40 x 256 floats = 40K) overlay [8K,48K), barrier-guarded.
    __shared__ __align__(16) char smem[49152];
    float4* tileA = (float4*)smem;                       // AoS, phase C/refine
    float4* tile2 = (float4*)(smem + 8192);              // pair-SoA, phase A
    float (*keys)[256] = (float(*)[256])(smem + 8192);   // 40 rows x 256

    const int tid = threadIdx.x;
    const int lane = tid & 63;
    const int wid_u = __builtin_amdgcn_readfirstlane(tid >> 6);  // wave 0-3
    const int b = blockIdx.x >> 7;             // 128 blocks per batch
    const int base = (blockIdx.x & 127) << 9;  // block covers 512 queries

    // ---- fused prep: build both table layouts from xyz2 (bit-identical) ----
    {
        const float* p = xyz2 + (size_t)b * 3 * S;
        float* t2f = (float*)tile2;
#pragma unroll
        for (int r = 0; r < 2; ++r) {
            int s = tid + r * 256;
            float x = p[s], y = p[s + S], z = p[s + 2 * S];
            float c = __fadd_rn(__fadd_rn(__fmul_rn(x, x), __fmul_rn(y, y)),
                                __fmul_rn(z, z));
            tileA[s] = make_float4(x, y, z, c);
            int pp = s >> 1, h = s & 1;
            t2f[pp * 8 + 0 + h] = x;
            t2f[pp * 8 + 2 + h] = y;
            t2f[pp * 8 + 4 + h] = z;
            t2f[pp * 8 + 6 + h] = c;
        }
    }
    __syncthreads();

    // 8 query slots per lane: n_s = base + s*64 + lane (coalesced loads)
    const int n_0 = base + lane;
    const float* q = xyz1 + (size_t)b * 3 * N;
#define MKC(s)                                                                     \
    float x_##s = q[n_0 + 64 * s], y_##s = q[n_0 + 64 * s + N],                    \
          z_##s = q[n_0 + 64 * s + 2 * N];                                         \
    float ss_##s = __fadd_rn(__fadd_rn(__fmul_rn(x_##s, x_##s),                    \
                                       __fmul_rn(y_##s, y_##s)),                   \
                             __fmul_rn(z_##s, z_##s));                             \
    float c_##s = ss_##s + 0.25f;                                                  \
    float nx_##s = -2.0f * x_##s, ny_##s = -2.0f * y_##s, nz_##s = -2.0f * z_##s;  \
    float2v nxp_##s = {nx_##s, nx_##s};                                            \
    float2v nyp_##s = {ny_##s, ny_##s};                                            \
    float2v nzp_##s = {nz_##s, nz_##s};                                            \
    float k##s##0 = 3.0e38f, k##s##1 = 3.0e38f, k##s##2 = 3.0e38f,                 \
          k##s##3 = 3.0e38f, k##s##4 = 3.0e38f;
    MKC(0) MKC(1) MKC(2) MKC(3) MKC(4) MKC(5) MKC(6) MKC(7)
#undef MKC

    uint32_t maskA = 0xFFFFFFC0u;     // VGPR mask -> single v_and_or_b32
    asm volatile("" : "+v"(maskA));

    // ---- Phase A: scan own 16 groups (pk distances); 5 best per slot ----
    const int gid0 = wid_u << 4;
#pragma unroll 2
    for (int g = 0; g < 16; ++g) {
        const int gid = gid0 + g;
        // group = 4 candidate pairs = 8 float4 (pair-SoA), broadcast b128
        float2v xs[4], ys[4], zs[4], ww[4];
#pragma unroll
        for (int k = 0; k < 4; ++k) {
            float4 pa = tile2[gid * 8 + 2 * k];      // {x_e,x_o,y_e,y_o}
            float4 pb = tile2[gid * 8 + 2 * k + 1];  // {z_e,z_o,w_e,w_o}
            xs[k] = (float2v){pa.x, pa.y};
            ys[k] = (float2v){pa.z, pa.w};
            zs[k] = (float2v){pb.x, pb.y};
            ww[k] = (float2v){pb.z, pb.w};
        }
        PK_PROC(0, gid) PK_PROC(1, gid) PK_PROC(2, gid) PK_PROC(3, gid)
        PK_PROC(4, gid) PK_PROC(5, gid) PK_PROC(6, gid) PK_PROC(7, gid)
    }

    // tile2 dead; keys overlay its space. Barrier so no wave still reads it.
    __syncthreads();

    // ---- publish all 40 keys ----
#define PUB(s)                                                       \
    keys[s * 5 + 0][tid] = k##s##0; keys[s * 5 + 1][tid] = k##s##1;  \
    keys[s * 5 + 2][tid] = k##s##2; keys[s * 5 + 3][tid] = k##s##3;  \
    keys[s * 5 + 4][tid] = k##s##4;
    PUB(0) PUB(1) PUB(2) PUB(3) PUB(4) PUB(5) PUB(6) PUB(7)
#undef PUB
    __syncthreads();

    // ---- merge + phase C: wave w owns slots 2w, 2w+1 ----
    const float* f = points2 + (size_t)b * S;  // D = 1
    if (wid_u == 0) {
        FIN(0, 64, 128, 192)
        FIN(1, 64, 128, 192)
    } else if (wid_u == 1) {
        FIN(2, 0, 128, 192)
        FIN(3, 0, 128, 192)
    } else if (wid_u == 2) {
        FIN(4, 0, 64, 192)
        FIN(5, 0, 64, 192)
    } else {
        FIN(6, 0, 64, 128)
        FIN(7, 0, 64, 128)
    }
}

extern "C" void kernel_launch(void* const* d_in, const int* in_sizes, int n_in,
                              void* d_out, int out_size, void* d_ws, size_t ws_size,
                              hipStream_t stream) {
    const float* xyz1 = (const float*)d_in[0];
    const float* xyz2 = (const float*)d_in[1];
    const float* points2 = (const float*)d_in[2];
    float* out = (float*)d_out;
    (void)d_ws; (void)ws_size;

    // 512 blocks x 256 threads: block covers 512 queries (Q=8 per lane),
    // candidates split 4 ways across the block's waves
    knn3_kernel<<<(B * N) / 512, 256, 0, stream>>>(xyz1, xyz2, points2, out);
}